// Round 1
// baseline (574.374 us; speedup 1.0000x reference)
//
#include <hip/hip_runtime.h>

typedef __attribute__((ext_vector_type(4))) float  f32x4;
typedef __attribute__((ext_vector_type(8))) short  s16x8;
typedef __attribute__((ext_vector_type(4))) int    i32x4;

#define MFMA16(a, b, c) __builtin_amdgcn_mfma_f32_16x16x32_bf16((a), (b), (c), 0, 0, 0)

__device__ __forceinline__ void gload_lds16(const void* g, void* l) {
  __builtin_amdgcn_global_load_lds((const __attribute__((address_space(1))) void*)g,
                                   (__attribute__((address_space(3))) void*)l, 16, 0, 0);
}

__device__ __forceinline__ unsigned short sgnbits(float v) {
  return v > 0.f ? (unsigned short)0x3F80u : (v < 0.f ? (unsigned short)0xBF80u : (unsigned short)0u);
}

// ---------------------------------------------------------------------------
// prep_w: per-oc scale = mean|w|; sign(w) as bf16.
//   blockIdx.y==0: w3x3 (C,C,3,3) -> w1s[tap][oc][ic];  scale1[oc]
//   blockIdx.y==1: wpw  (C,C,1,1) -> w2s[oc][ic];        scale2[oc]
// ---------------------------------------------------------------------------
__global__ __launch_bounds__(256) void prep_w(const float* __restrict__ w3,
                                              const float* __restrict__ wpw,
                                              unsigned short* __restrict__ w1s,
                                              unsigned short* __restrict__ w2s,
                                              float* __restrict__ scale1,
                                              float* __restrict__ scale2) {
  const int o = blockIdx.x;
  const int t = threadIdx.x;
  float s = 0.f;
  if (blockIdx.y == 0) {
    for (int u = t; u < 2304; u += 256) {
      int i = u / 9, tap = u % 9;
      float v = w3[(size_t)(o * 256 + i) * 9 + tap];
      s += fabsf(v);
      w1s[(size_t)(tap * 256 + o) * 256 + i] = sgnbits(v);
    }
  } else {
    float v = wpw[o * 256 + t];
    s = fabsf(v);
    w2s[o * 256 + t] = sgnbits(v);
  }
  for (int m = 1; m < 64; m <<= 1) s += __shfl_xor(s, m);
  __shared__ float red[4];
  if ((t & 63) == 0) red[t >> 6] = s;
  __syncthreads();
  if (t == 0) {
    float tot = red[0] + red[1] + red[2] + red[3];
    if (blockIdx.y == 0) scale1[o] = tot / 2304.f;
    else                 scale2[o] = tot / 256.f;
  }
}

// ---------------------------------------------------------------------------
// sign_nhwc: s1[n][h][w][c] = bf16(sign(x[n][c][h][w] + b11[c]))
// block = (h, n); LDS transpose 256c x 56w -> [w][c]
// ---------------------------------------------------------------------------
__global__ __launch_bounds__(256) void sign_nhwc(const float* __restrict__ x,
                                                 const float* __restrict__ b11,
                                                 unsigned short* __restrict__ out) {
  __shared__ unsigned short l[56 * 264];  // [w][264] (+8 pad shorts vs 256)
  const int h = blockIdx.x, n = blockIdx.y, t = threadIdx.x;
  const int cw = t >> 6, w = t & 63;
  if (w < 56) {
    const float* xp = x + (size_t)n * 256 * 3136 + h * 56 + w;
#pragma unroll 8
    for (int it = 0; it < 64; ++it) {
      int c = it * 4 + cw;
      float v = xp[(size_t)c * 3136] + b11[c];
      l[w * 264 + c] = sgnbits(v);
    }
  }
  __syncthreads();
  unsigned short* op = out + ((size_t)(n * 56 + h) * 56) * 256;
  for (int u = t; u < 56 * 32; u += 256) {
    int w2 = u >> 5, cp = u & 31;
    *(i32x4*)(op + w2 * 256 + cp * 8) = *(const i32x4*)&l[w2 * 264 + cp * 8];
  }
}

// ---------------------------------------------------------------------------
// conv_bin<R>: implicit-GEMM binary conv. R=1: 3x3 pad1. R=0: 1x1 pad0.
// Input  sIn: NHWC bf16 signs [32][56][56][256]
// Weight wSgn: [taps][256][256] bf16 signs
// Output raw:  NCHW f32 integer sums; stats S/SS per oc (atomics).
// Block: 64 oc x (4 rows x 56 px) = 64x224. 4 waves: (wm,wn) -> 32oc x 112px.
// ---------------------------------------------------------------------------
template <int R>
__global__ __launch_bounds__(256, 2) void conv_bin(const unsigned short* __restrict__ sIn,
                                                   const unsigned short* __restrict__ wSgn,
                                                   float* __restrict__ raw,
                                                   float* __restrict__ S,
                                                   float* __restrict__ SS) {
  constexpr int KD   = 2 * R + 1;
  constexpr int TAPS = KD * KD;
  constexpr int ROWS = 4 + 2 * R;
  constexpr int COLS = 56 + 2 * R;
  __shared__ unsigned short lin[ROWS * COLS * 32];  // [row][col][ic32]
  __shared__ unsigned short lw[TAPS * 64 * 32];     // [tap][oc64][ic32]

  const int ot = blockIdx.x, ht = blockIdx.y, n = blockIdx.z;
  const int h0 = ht * 4, oc0 = ot * 64;
  const int t = threadIdx.x;
  const int lane = t & 63, wv = t >> 6;
  const int wm = wv & 1, wn = wv >> 1;
  const int cl = lane & 15, kk = lane >> 4;

  // zero input LDS once (persistent halo padding)
  for (int u = t; u < ROWS * COLS * 4; u += 256)
    *(i32x4*)((char*)lin + (size_t)u * 16) = (i32x4){0, 0, 0, 0};

  // per-lane B-fragment base offsets (bytes into lin)
  int bbase[7];
#pragma unroll
  for (int nf = 0; nf < 7; ++nf) {
    int pxl = (wn * 7 + nf) * 16 + cl;
    int r = pxl / 56, c = pxl % 56;
    bbase[nf] = (r * COLS + c) * 64 + kk * 16;
  }
  const int abase = (wm * 32 + cl) * 64 + kk * 16;  // + m*1024 + tap*4096

  f32x4 acc[2][7];
#pragma unroll
  for (int m = 0; m < 2; ++m)
#pragma unroll
    for (int nf = 0; nf < 7; ++nf) acc[m][nf] = (f32x4){0.f, 0.f, 0.f, 0.f};

  __syncthreads();

  for (int icc = 0; icc < 8; ++icc) {
    // stage input rows (valid region only; halo stays zero)
#pragma unroll
    for (int rr = 0; rr < ROWS; ++rr) {
      int h = h0 - R + rr;
      if (h >= 0 && h < 56 && t < 224) {
        const char* src = (const char*)sIn +
            ((size_t)((n * 56 + h) * 56 + (t >> 2)) * 512 + icc * 64 + (t & 3) * 16);
        char* dst = (char*)lin + ((rr * COLS + R) * 64 + t * 16);
        gload_lds16(src, dst);
      }
    }
    // stage weights [tap][oc64][ic32]
    for (int u = t; u < TAPS * 256; u += 256) {
      int tap = u >> 8, rest = u & 255;
      const char* src = (const char*)wSgn +
          ((size_t)(tap * 256 + oc0 + (rest >> 2)) * 512 + icc * 64 + (rest & 3) * 16);
      gload_lds16(src, (char*)lw + (size_t)u * 16);
    }
    __syncthreads();

#pragma unroll
    for (int kh = 0; kh < KD; ++kh)
#pragma unroll
      for (int kw = 0; kw < KD; ++kw) {
        const int tap = kh * KD + kw;
        s16x8 a0 = *(const s16x8*)((const char*)lw + (tap * 4096 + abase));
        s16x8 a1 = *(const s16x8*)((const char*)lw + (tap * 4096 + abase + 1024));
        const int toff = (kh * COLS + kw) * 64;
#pragma unroll
        for (int nf = 0; nf < 7; ++nf) {
          s16x8 b = *(const s16x8*)((const char*)lin + (bbase[nf] + toff));
          acc[0][nf] = MFMA16(a0, b, acc[0][nf]);
          acc[1][nf] = MFMA16(a1, b, acc[1][nf]);
        }
      }
    __syncthreads();
  }

  // epilogue: store raw + per-oc stats
  float sm[2][4], sq[2][4];
#pragma unroll
  for (int m = 0; m < 2; ++m)
#pragma unroll
    for (int r2 = 0; r2 < 4; ++r2) { sm[m][r2] = 0.f; sq[m][r2] = 0.f; }

  const size_t pbase = (size_t)n * 256 * 3136 + (size_t)h0 * 56;
#pragma unroll
  for (int m = 0; m < 2; ++m) {
    const int ocb = oc0 + wm * 32 + m * 16 + kk * 4;
#pragma unroll
    for (int nf = 0; nf < 7; ++nf) {
      const int pxl = (wn * 7 + nf) * 16 + cl;
      f32x4 v = acc[m][nf];
#pragma unroll
      for (int r2 = 0; r2 < 4; ++r2) {
        raw[pbase + (size_t)(ocb + r2) * 3136 + pxl] = v[r2];
        sm[m][r2] += v[r2];
        sq[m][r2] += v[r2] * v[r2];
      }
    }
  }
#pragma unroll
  for (int m = 0; m < 2; ++m)
#pragma unroll
    for (int r2 = 0; r2 < 4; ++r2) {
      float a = sm[m][r2], q = sq[m][r2];
      a += __shfl_xor(a, 1); q += __shfl_xor(q, 1);
      a += __shfl_xor(a, 2); q += __shfl_xor(q, 2);
      a += __shfl_xor(a, 4); q += __shfl_xor(q, 4);
      a += __shfl_xor(a, 8); q += __shfl_xor(q, 8);
      if (cl == 0) {
        int oc = oc0 + wm * 32 + m * 16 + kk * 4 + r2;
        atomicAdd(&S[oc], a);
        atomicAdd(&SS[oc], q);
      }
    }
}

// ---------------------------------------------------------------------------
// bn_coef: fold batch stats + binarization scale + BN affine into A*raw+B
// ---------------------------------------------------------------------------
__global__ void bn_coef(const float* __restrict__ S, const float* __restrict__ SS,
                        const float* __restrict__ scale, const float* __restrict__ g,
                        const float* __restrict__ be, float* __restrict__ A,
                        float* __restrict__ B) {
  int o = threadIdx.x;
  const float invN = 1.f / 100352.f;
  float mu_r  = S[o] * invN;
  float var_r = SS[o] * invN - mu_r * mu_r;
  float sc    = scale[o];
  float rstd  = rsqrtf(sc * sc * var_r + 1e-5f);
  A[o] = g[o] * rstd * sc;
  B[o] = be[o] - g[o] * rstd * sc * mu_r;
}

// ---------------------------------------------------------------------------
// mid_fuse: t1 = prelu(x + A1*raw + B1 + b12, p1) + b13  (NCHW f32, -> d_out)
//           s2 = bf16(sign(t1 + b21))  (NHWC, LDS transpose)
// ---------------------------------------------------------------------------
__global__ __launch_bounds__(256) void mid_fuse(const float* __restrict__ raw,
                                                const float* __restrict__ x,
                                                const float* __restrict__ A1,
                                                const float* __restrict__ B1,
                                                const float* __restrict__ b12,
                                                const float* __restrict__ p1,
                                                const float* __restrict__ b13,
                                                const float* __restrict__ b21,
                                                float* __restrict__ t1,
                                                unsigned short* __restrict__ s2) {
  __shared__ unsigned short l[56 * 264];
  const int h = blockIdx.x, n = blockIdx.y, t = threadIdx.x;
  const int cw = t >> 6, w = t & 63;
  if (w < 56) {
    const size_t base = (size_t)n * 256 * 3136 + h * 56 + w;
#pragma unroll 4
    for (int it = 0; it < 64; ++it) {
      int c = it * 4 + cw;
      size_t idx = base + (size_t)c * 3136;
      float v = x[idx] + A1[c] * raw[idx] + B1[c];
      float u = v + b12[c];
      u = (u >= 0.f ? u : p1[c] * u) + b13[c];
      t1[idx] = u;
      l[w * 264 + c] = sgnbits(u + b21[c]);
    }
  }
  __syncthreads();
  unsigned short* op = s2 + ((size_t)(n * 56 + h) * 56) * 256;
  for (int uu = t; uu < 56 * 32; uu += 256) {
    int w2 = uu >> 5, cp = uu & 31;
    *(i32x4*)(op + w2 * 256 + cp * 8) = *(const i32x4*)&l[w2 * 264 + cp * 8];
  }
}

// ---------------------------------------------------------------------------
// final_fuse: out = prelu(A2*raw + B2 + t1 + b22, p2) + b23  (in-place on d_out)
// ---------------------------------------------------------------------------
__global__ __launch_bounds__(256) void final_fuse(const float* __restrict__ raw,
                                                  const float* __restrict__ A2,
                                                  const float* __restrict__ B2,
                                                  const float* __restrict__ b22,
                                                  const float* __restrict__ p2,
                                                  const float* __restrict__ b23,
                                                  float* out) {
  const int total4 = 25690112 / 4;
  for (int i = blockIdx.x * 256 + threadIdx.x; i < total4; i += gridDim.x * 256) {
    int c = ((i * 4) / 3136) & 255;
    f32x4 r  = *(const f32x4*)(raw + (size_t)i * 4);
    f32x4 tt = *(const f32x4*)(out + (size_t)i * 4);
    float a = A2[c], b = B2[c], bb = b22[c], p = p2[c], b3 = b23[c];
    f32x4 o;
#pragma unroll
    for (int j = 0; j < 4; ++j) {
      float v = a * r[j] + b + tt[j] + bb;
      o[j] = (v >= 0.f ? v : p * v) + b3;
    }
    *(f32x4*)(out + (size_t)i * 4) = o;
  }
}

// ---------------------------------------------------------------------------
extern "C" void kernel_launch(void* const* d_in, const int* in_sizes, int n_in,
                              void* d_out, int out_size, void* d_ws, size_t ws_size,
                              hipStream_t stream) {
  const float* x   = (const float*)d_in[0];
  const float* b11 = (const float*)d_in[1];
  const float* b12 = (const float*)d_in[2];
  const float* b13 = (const float*)d_in[3];
  const float* b21 = (const float*)d_in[4];
  const float* b22 = (const float*)d_in[5];
  const float* b23 = (const float*)d_in[6];
  const float* w3  = (const float*)d_in[7];
  const float* wpw = (const float*)d_in[8];
  const float* g1  = (const float*)d_in[9];
  const float* be1 = (const float*)d_in[10];
  const float* g2  = (const float*)d_in[11];
  const float* be2 = (const float*)d_in[12];
  const float* p1  = (const float*)d_in[13];
  const float* p2  = (const float*)d_in[14];

  char* ws = (char*)d_ws;
  float*          raw    = (float*)(ws);                      // 102,760,448 B
  unsigned short* sgn    = (unsigned short*)(ws + 102760448); //  51,380,224 B
  unsigned short* w1s    = (unsigned short*)(ws + 154140672); //   1,179,648 B
  unsigned short* w2s    = (unsigned short*)(ws + 155320320); //     131,072 B
  float*          scale1 = (float*)(ws + 155451392);
  float*          scale2 = (float*)(ws + 155452416);
  float*          S1     = (float*)(ws + 155453440);
  float*          SS1    = (float*)(ws + 155454464);
  float*          S2     = (float*)(ws + 155455488);
  float*          SS2    = (float*)(ws + 155456512);
  float*          A1     = (float*)(ws + 155457536);
  float*          B1     = (float*)(ws + 155458560);
  float*          A2     = (float*)(ws + 155459584);
  float*          B2     = (float*)(ws + 155460608);
  float*          t1     = (float*)d_out;

  hipMemsetAsync(ws + 155453440, 0, 4096, stream);  // zero S1,SS1,S2,SS2

  prep_w<<<dim3(256, 2), 256, 0, stream>>>(w3, wpw, w1s, w2s, scale1, scale2);
  sign_nhwc<<<dim3(56, 32), 256, 0, stream>>>(x, b11, sgn);
  conv_bin<1><<<dim3(4, 14, 32), 256, 0, stream>>>(sgn, w1s, raw, S1, SS1);
  bn_coef<<<1, 256, 0, stream>>>(S1, SS1, scale1, g1, be1, A1, B1);
  mid_fuse<<<dim3(56, 32), 256, 0, stream>>>(raw, x, A1, B1, b12, p1, b13, b21, t1, sgn);
  conv_bin<0><<<dim3(4, 14, 32), 256, 0, stream>>>(sgn, w2s, raw, S2, SS2);
  bn_coef<<<1, 256, 0, stream>>>(S2, SS2, scale2, g2, be2, A2, B2);
  final_fuse<<<dim3(4096), 256, 0, stream>>>(raw, A2, B2, b22, p2, b23, (float*)d_out);
}

// Round 2
// 471.155 us; speedup vs baseline: 1.2191x; 1.2191x over previous
//
#include <hip/hip_runtime.h>

typedef __attribute__((ext_vector_type(4))) float  f32x4;
typedef __attribute__((ext_vector_type(8))) short  s16x8;
typedef __attribute__((ext_vector_type(4))) int    i32x4;

#define MFMA16(a, b, c) __builtin_amdgcn_mfma_f32_16x16x32_bf16((a), (b), (c), 0, 0, 0)

__device__ __forceinline__ void gload_lds16(const void* g, void* l) {
  __builtin_amdgcn_global_load_lds((const __attribute__((address_space(1))) void*)g,
                                   (__attribute__((address_space(3))) void*)l, 16, 0, 0);
}

__device__ __forceinline__ unsigned short sgnbits(float v) {
  return v > 0.f ? (unsigned short)0x3F80u : (v < 0.f ? (unsigned short)0xBF80u : (unsigned short)0u);
}

// ---------------------------------------------------------------------------
// prep_w: per-oc scale = mean|w|; sign(w) as bf16.
// ---------------------------------------------------------------------------
__global__ __launch_bounds__(256) void prep_w(const float* __restrict__ w3,
                                              const float* __restrict__ wpw,
                                              unsigned short* __restrict__ w1s,
                                              unsigned short* __restrict__ w2s,
                                              float* __restrict__ scale1,
                                              float* __restrict__ scale2) {
  const int o = blockIdx.x;
  const int t = threadIdx.x;
  float s = 0.f;
  if (blockIdx.y == 0) {
    for (int u = t; u < 2304; u += 256) {
      int i = u / 9, tap = u % 9;
      float v = w3[(size_t)(o * 256 + i) * 9 + tap];
      s += fabsf(v);
      w1s[(size_t)(tap * 256 + o) * 256 + i] = sgnbits(v);
    }
  } else {
    float v = wpw[o * 256 + t];
    s = fabsf(v);
    w2s[o * 256 + t] = sgnbits(v);
  }
  for (int m = 1; m < 64; m <<= 1) s += __shfl_xor(s, m);
  __shared__ float red[4];
  if ((t & 63) == 0) red[t >> 6] = s;
  __syncthreads();
  if (t == 0) {
    float tot = red[0] + red[1] + red[2] + red[3];
    if (blockIdx.y == 0) scale1[o] = tot / 2304.f;
    else                 scale2[o] = tot / 256.f;
  }
}

// ---------------------------------------------------------------------------
// sign_nhwc: s1[n][h][w][c] = bf16(sign(x[n][c][h][w] + b11[c]))
// vec4 loads along W; coeffs in LDS; XOR-swizzled transpose buffer.
// ---------------------------------------------------------------------------
__global__ __launch_bounds__(256) void sign_nhwc(const float* __restrict__ x,
                                                 const float* __restrict__ b11,
                                                 unsigned short* __restrict__ out) {
  __shared__ unsigned short l[56 * 256];
  __shared__ float cB[256];
  const int h = blockIdx.x, n = blockIdx.y, t = threadIdx.x;
  cB[t] = b11[t];
  __syncthreads();
  const int wv = t & 15, cg = t >> 4;
  if (wv < 14) {
    const int w0 = wv * 4;
    const int swz = (wv & 7) << 3;
#pragma unroll 4
    for (int it = 0; it < 16; ++it) {
      int c = it * 16 + cg;
      size_t idx = (size_t)(n * 256 + c) * 3136 + h * 56 + w0;
      f32x4 xv = *(const f32x4*)(x + idx);
      float bb = cB[c];
      int cs = c ^ swz;
      l[(w0 + 0) * 256 + cs] = sgnbits(xv[0] + bb);
      l[(w0 + 1) * 256 + cs] = sgnbits(xv[1] + bb);
      l[(w0 + 2) * 256 + cs] = sgnbits(xv[2] + bb);
      l[(w0 + 3) * 256 + cs] = sgnbits(xv[3] + bb);
    }
  }
  __syncthreads();
  unsigned short* op = out + ((size_t)(n * 56 + h) * 56) * 256;
  for (int u = t; u < 56 * 32; u += 256) {
    int w2 = u >> 5, cp = u & 31;
    *(i32x4*)(op + w2 * 256 + cp * 8) =
        *(const i32x4*)&l[w2 * 256 + ((cp * 8) ^ (((w2 >> 2) & 7) << 3))];
  }
}

// ---------------------------------------------------------------------------
// conv_bin<R>: implicit-GEMM binary conv (unchanged this round).
// ---------------------------------------------------------------------------
template <int R>
__global__ __launch_bounds__(256, 2) void conv_bin(const unsigned short* __restrict__ sIn,
                                                   const unsigned short* __restrict__ wSgn,
                                                   float* __restrict__ raw,
                                                   float* __restrict__ S,
                                                   float* __restrict__ SS) {
  constexpr int KD   = 2 * R + 1;
  constexpr int TAPS = KD * KD;
  constexpr int ROWS = 4 + 2 * R;
  constexpr int COLS = 56 + 2 * R;
  __shared__ unsigned short lin[ROWS * COLS * 32];
  __shared__ unsigned short lw[TAPS * 64 * 32];

  const int ot = blockIdx.x, ht = blockIdx.y, n = blockIdx.z;
  const int h0 = ht * 4, oc0 = ot * 64;
  const int t = threadIdx.x;
  const int lane = t & 63, wv = t >> 6;
  const int wm = wv & 1, wn = wv >> 1;
  const int cl = lane & 15, kk = lane >> 4;

  for (int u = t; u < ROWS * COLS * 4; u += 256)
    *(i32x4*)((char*)lin + (size_t)u * 16) = (i32x4){0, 0, 0, 0};

  int bbase[7];
#pragma unroll
  for (int nf = 0; nf < 7; ++nf) {
    int pxl = (wn * 7 + nf) * 16 + cl;
    int r = pxl / 56, c = pxl % 56;
    bbase[nf] = (r * COLS + c) * 64 + kk * 16;
  }
  const int abase = (wm * 32 + cl) * 64 + kk * 16;

  f32x4 acc[2][7];
#pragma unroll
  for (int m = 0; m < 2; ++m)
#pragma unroll
    for (int nf = 0; nf < 7; ++nf) acc[m][nf] = (f32x4){0.f, 0.f, 0.f, 0.f};

  __syncthreads();

  for (int icc = 0; icc < 8; ++icc) {
#pragma unroll
    for (int rr = 0; rr < ROWS; ++rr) {
      int h = h0 - R + rr;
      if (h >= 0 && h < 56 && t < 224) {
        const char* src = (const char*)sIn +
            ((size_t)((n * 56 + h) * 56 + (t >> 2)) * 512 + icc * 64 + (t & 3) * 16);
        char* dst = (char*)lin + ((rr * COLS + R) * 64 + t * 16);
        gload_lds16(src, dst);
      }
    }
    for (int u = t; u < TAPS * 256; u += 256) {
      int tap = u >> 8, rest = u & 255;
      const char* src = (const char*)wSgn +
          ((size_t)(tap * 256 + oc0 + (rest >> 2)) * 512 + icc * 64 + (rest & 3) * 16);
      gload_lds16(src, (char*)lw + (size_t)u * 16);
    }
    __syncthreads();

#pragma unroll
    for (int kh = 0; kh < KD; ++kh)
#pragma unroll
      for (int kw = 0; kw < KD; ++kw) {
        const int tap = kh * KD + kw;
        s16x8 a0 = *(const s16x8*)((const char*)lw + (tap * 4096 + abase));
        s16x8 a1 = *(const s16x8*)((const char*)lw + (tap * 4096 + abase + 1024));
        const int toff = (kh * COLS + kw) * 64;
#pragma unroll
        for (int nf = 0; nf < 7; ++nf) {
          s16x8 b = *(const s16x8*)((const char*)lin + (bbase[nf] + toff));
          acc[0][nf] = MFMA16(a0, b, acc[0][nf]);
          acc[1][nf] = MFMA16(a1, b, acc[1][nf]);
        }
      }
    __syncthreads();
  }

  float sm[2][4], sq[2][4];
#pragma unroll
  for (int m = 0; m < 2; ++m)
#pragma unroll
    for (int r2 = 0; r2 < 4; ++r2) { sm[m][r2] = 0.f; sq[m][r2] = 0.f; }

  const size_t pbase = (size_t)n * 256 * 3136 + (size_t)h0 * 56;
#pragma unroll
  for (int m = 0; m < 2; ++m) {
    const int ocb = oc0 + wm * 32 + m * 16 + kk * 4;
#pragma unroll
    for (int nf = 0; nf < 7; ++nf) {
      const int pxl = (wn * 7 + nf) * 16 + cl;
      f32x4 v = acc[m][nf];
#pragma unroll
      for (int r2 = 0; r2 < 4; ++r2) {
        raw[pbase + (size_t)(ocb + r2) * 3136 + pxl] = v[r2];
        sm[m][r2] += v[r2];
        sq[m][r2] += v[r2] * v[r2];
      }
    }
  }
#pragma unroll
  for (int m = 0; m < 2; ++m)
#pragma unroll
    for (int r2 = 0; r2 < 4; ++r2) {
      float a = sm[m][r2], q = sq[m][r2];
      a += __shfl_xor(a, 1); q += __shfl_xor(q, 1);
      a += __shfl_xor(a, 2); q += __shfl_xor(q, 2);
      a += __shfl_xor(a, 4); q += __shfl_xor(q, 4);
      a += __shfl_xor(a, 8); q += __shfl_xor(q, 8);
      if (cl == 0) {
        int oc = oc0 + wm * 32 + m * 16 + kk * 4 + r2;
        atomicAdd(&S[oc], a);
        atomicAdd(&SS[oc], q);
      }
    }
}

// ---------------------------------------------------------------------------
// bn_coef: fold stats + scale + BN affine + following bias into A*raw + B
// ---------------------------------------------------------------------------
__global__ void bn_coef(const float* __restrict__ S, const float* __restrict__ SS,
                        const float* __restrict__ scale, const float* __restrict__ g,
                        const float* __restrict__ be, const float* __restrict__ bext,
                        float* __restrict__ A, float* __restrict__ B) {
  int o = threadIdx.x;
  const float invN = 1.f / 100352.f;
  float mu_r  = S[o] * invN;
  float var_r = SS[o] * invN - mu_r * mu_r;
  float sc    = scale[o];
  float rstd  = rsqrtf(sc * sc * var_r + 1e-5f);
  A[o] = g[o] * rstd * sc;
  B[o] = be[o] - g[o] * rstd * sc * mu_r + bext[o];
}

// ---------------------------------------------------------------------------
// mid_fuse: u = prelu(x + A1*raw + B1', p1) + b13 -> t1 (d_out, NCHW)
//           s2 = bf16(sign(u + b21)) (NHWC via swizzled LDS transpose)
// vec4 loads, coeffs in LDS.
// ---------------------------------------------------------------------------
__global__ __launch_bounds__(256) void mid_fuse(const float* __restrict__ raw,
                                                const float* __restrict__ x,
                                                const float* __restrict__ A1,
                                                const float* __restrict__ B1,
                                                const float* __restrict__ p1,
                                                const float* __restrict__ b13,
                                                const float* __restrict__ b21,
                                                float* __restrict__ t1,
                                                unsigned short* __restrict__ s2) {
  __shared__ unsigned short l[56 * 256];
  __shared__ float cA[256], cB[256], cP[256], cD[256], cE[256];
  const int h = blockIdx.x, n = blockIdx.y, t = threadIdx.x;
  cA[t] = A1[t]; cB[t] = B1[t]; cP[t] = p1[t]; cD[t] = b13[t]; cE[t] = b21[t];
  __syncthreads();
  const int wv = t & 15, cg = t >> 4;
  if (wv < 14) {
    const int w0 = wv * 4;
    const int swz = (wv & 7) << 3;
#pragma unroll 4
    for (int it = 0; it < 16; ++it) {
      int c = it * 16 + cg;
      size_t idx = (size_t)(n * 256 + c) * 3136 + h * 56 + w0;
      f32x4 xv = *(const f32x4*)(x + idx);
      f32x4 rv = *(const f32x4*)(raw + idx);
      float a = cA[c], b = cB[c], p = cP[c], d = cD[c], e = cE[c];
      f32x4 o;
      int cs = c ^ swz;
#pragma unroll
      for (int j = 0; j < 4; ++j) {
        float u = xv[j] + a * rv[j] + b;
        u = (u >= 0.f ? u : p * u) + d;
        o[j] = u;
        l[(w0 + j) * 256 + cs] = sgnbits(u + e);
      }
      *(f32x4*)(t1 + idx) = o;
    }
  }
  __syncthreads();
  unsigned short* op = s2 + ((size_t)(n * 56 + h) * 56) * 256;
  for (int u = t; u < 56 * 32; u += 256) {
    int w2 = u >> 5, cp = u & 31;
    *(i32x4*)(op + w2 * 256 + cp * 8) =
        *(const i32x4*)&l[w2 * 256 + ((cp * 8) ^ (((w2 >> 2) & 7) << 3))];
  }
}

// ---------------------------------------------------------------------------
// final_fuse: out = prelu(A2*raw + B2' + t1, p2) + b23  (block per (n,c) plane)
// ---------------------------------------------------------------------------
__global__ __launch_bounds__(256) void final_fuse(const float* __restrict__ raw,
                                                  const float* __restrict__ A2,
                                                  const float* __restrict__ B2,
                                                  const float* __restrict__ p2,
                                                  const float* __restrict__ b23,
                                                  float* out) {
  const int c = blockIdx.x & 255;
  const size_t base = (size_t)blockIdx.x * 3136;
  const float a = A2[c], b = B2[c], p = p2[c], d = b23[c];
  for (int i = threadIdx.x; i < 784; i += 256) {
    f32x4 r  = *(const f32x4*)(raw + base + (size_t)i * 4);
    f32x4 tt = *(const f32x4*)(out + base + (size_t)i * 4);
    f32x4 o;
#pragma unroll
    for (int j = 0; j < 4; ++j) {
      float v = a * r[j] + b + tt[j];
      o[j] = (v >= 0.f ? v : p * v) + d;
    }
    *(f32x4*)(out + base + (size_t)i * 4) = o;
  }
}

// ---------------------------------------------------------------------------
extern "C" void kernel_launch(void* const* d_in, const int* in_sizes, int n_in,
                              void* d_out, int out_size, void* d_ws, size_t ws_size,
                              hipStream_t stream) {
  const float* x   = (const float*)d_in[0];
  const float* b11 = (const float*)d_in[1];
  const float* b12 = (const float*)d_in[2];
  const float* b13 = (const float*)d_in[3];
  const float* b21 = (const float*)d_in[4];
  const float* b22 = (const float*)d_in[5];
  const float* b23 = (const float*)d_in[6];
  const float* w3  = (const float*)d_in[7];
  const float* wpw = (const float*)d_in[8];
  const float* g1  = (const float*)d_in[9];
  const float* be1 = (const float*)d_in[10];
  const float* g2  = (const float*)d_in[11];
  const float* be2 = (const float*)d_in[12];
  const float* p1  = (const float*)d_in[13];
  const float* p2  = (const float*)d_in[14];

  char* ws = (char*)d_ws;
  float*          raw    = (float*)(ws);                      // 102,760,448 B
  unsigned short* sgn    = (unsigned short*)(ws + 102760448); //  51,380,224 B
  unsigned short* w1s    = (unsigned short*)(ws + 154140672); //   1,179,648 B
  unsigned short* w2s    = (unsigned short*)(ws + 155320320); //     131,072 B
  float*          scale1 = (float*)(ws + 155451392);
  float*          scale2 = (float*)(ws + 155452416);
  float*          S1     = (float*)(ws + 155453440);
  float*          SS1    = (float*)(ws + 155454464);
  float*          S2     = (float*)(ws + 155455488);
  float*          SS2    = (float*)(ws + 155456512);
  float*          A1     = (float*)(ws + 155457536);
  float*          B1     = (float*)(ws + 155458560);
  float*          A2     = (float*)(ws + 155459584);
  float*          B2     = (float*)(ws + 155460608);
  float*          t1     = (float*)d_out;

  hipMemsetAsync(ws + 155453440, 0, 4096, stream);  // zero S1,SS1,S2,SS2

  prep_w<<<dim3(256, 2), 256, 0, stream>>>(w3, wpw, w1s, w2s, scale1, scale2);
  sign_nhwc<<<dim3(56, 32), 256, 0, stream>>>(x, b11, sgn);
  conv_bin<1><<<dim3(4, 14, 32), 256, 0, stream>>>(sgn, w1s, raw, S1, SS1);
  bn_coef<<<1, 256, 0, stream>>>(S1, SS1, scale1, g1, be1, b12, A1, B1);
  mid_fuse<<<dim3(56, 32), 256, 0, stream>>>(raw, x, A1, B1, p1, b13, b21, t1, sgn);
  conv_bin<0><<<dim3(4, 14, 32), 256, 0, stream>>>(sgn, w2s, raw, S2, SS2);
  bn_coef<<<1, 256, 0, stream>>>(S2, SS2, scale2, g2, be2, b22, A2, B2);
  final_fuse<<<dim3(8192), 256, 0, stream>>>(raw, A2, B2, p2, b23, (float*)d_out);
}

// Round 3
// 434.389 us; speedup vs baseline: 1.3223x; 1.0846x over previous
//
#include <hip/hip_runtime.h>

typedef __attribute__((ext_vector_type(4))) float  f32x4;
typedef __attribute__((ext_vector_type(8))) short  s16x8;
typedef __attribute__((ext_vector_type(4))) short  s16x4;
typedef __attribute__((ext_vector_type(4))) int    i32x4;

#define MFMA16(a, b, c) __builtin_amdgcn_mfma_f32_16x16x32_bf16((a), (b), (c), 0, 0, 0)

__device__ __forceinline__ void gload_lds16(const void* g, void* l) {
  __builtin_amdgcn_global_load_lds((const __attribute__((address_space(1))) void*)g,
                                   (__attribute__((address_space(3))) void*)l, 16, 0, 0);
}

__device__ __forceinline__ unsigned short sgnbits(float v) {
  return v > 0.f ? (unsigned short)0x3F80u : (v < 0.f ? (unsigned short)0xBF80u : (unsigned short)0u);
}

// ---------------------------------------------------------------------------
// prep_w: per-oc scale = mean|w|; sign(w) as bf16.
// ---------------------------------------------------------------------------
__global__ __launch_bounds__(256) void prep_w(const float* __restrict__ w3,
                                              const float* __restrict__ wpw,
                                              unsigned short* __restrict__ w1s,
                                              unsigned short* __restrict__ w2s,
                                              float* __restrict__ scale1,
                                              float* __restrict__ scale2) {
  const int o = blockIdx.x;
  const int t = threadIdx.x;
  float s = 0.f;
  if (blockIdx.y == 0) {
    for (int u = t; u < 2304; u += 256) {
      int i = u / 9, tap = u % 9;
      float v = w3[(size_t)(o * 256 + i) * 9 + tap];
      s += fabsf(v);
      w1s[(size_t)(tap * 256 + o) * 256 + i] = sgnbits(v);
    }
  } else {
    float v = wpw[o * 256 + t];
    s = fabsf(v);
    w2s[o * 256 + t] = sgnbits(v);
  }
  for (int m = 1; m < 64; m <<= 1) s += __shfl_xor(s, m);
  __shared__ float red[4];
  if ((t & 63) == 0) red[t >> 6] = s;
  __syncthreads();
  if (t == 0) {
    float tot = red[0] + red[1] + red[2] + red[3];
    if (blockIdx.y == 0) scale1[o] = tot / 2304.f;
    else                 scale2[o] = tot / 256.f;
  }
}

// ---------------------------------------------------------------------------
// sign_nhwc: s1[n][h][w][c] = bf16(sign(x[n][c][h][w] + b11[c]))  (unchanged)
// ---------------------------------------------------------------------------
__global__ __launch_bounds__(256) void sign_nhwc(const float* __restrict__ x,
                                                 const float* __restrict__ b11,
                                                 unsigned short* __restrict__ out) {
  __shared__ unsigned short l[56 * 256];
  __shared__ float cB[256];
  const int h = blockIdx.x, n = blockIdx.y, t = threadIdx.x;
  cB[t] = b11[t];
  __syncthreads();
  const int wv = t & 15, cg = t >> 4;
  if (wv < 14) {
    const int w0 = wv * 4;
    const int swz = (wv & 7) << 3;
#pragma unroll 4
    for (int it = 0; it < 16; ++it) {
      int c = it * 16 + cg;
      size_t idx = (size_t)(n * 256 + c) * 3136 + h * 56 + w0;
      f32x4 xv = *(const f32x4*)(x + idx);
      float bb = cB[c];
      int cs = c ^ swz;
      l[(w0 + 0) * 256 + cs] = sgnbits(xv[0] + bb);
      l[(w0 + 1) * 256 + cs] = sgnbits(xv[1] + bb);
      l[(w0 + 2) * 256 + cs] = sgnbits(xv[2] + bb);
      l[(w0 + 3) * 256 + cs] = sgnbits(xv[3] + bb);
    }
  }
  __syncthreads();
  unsigned short* op = out + ((size_t)(n * 56 + h) * 56) * 256;
  for (int u = t; u < 56 * 32; u += 256) {
    int w2 = u >> 5, cp = u & 31;
    *(i32x4*)(op + w2 * 256 + cp * 8) =
        *(const i32x4*)&l[w2 * 256 + ((cp * 8) ^ (((w2 >> 2) & 7) << 3))];
  }
}

// ---------------------------------------------------------------------------
// conv3x3: implicit-GEMM binary conv, 3x3 pad1.
// Block: 64 oc x 448 px (8 rows x 56). 4 waves = 4 px-groups.
// Wave: m=4 frags (64 oc) x nf=7 (112 px). LDS slot-XOR swizzle (conflict-free).
// Output raw int16 NCHW + per-oc stats.
// ---------------------------------------------------------------------------
__global__ __launch_bounds__(256, 2) void conv3x3(const unsigned short* __restrict__ sIn,
                                                  const unsigned short* __restrict__ wSgn,
                                                  short* __restrict__ raw,
                                                  float* __restrict__ S,
                                                  float* __restrict__ SS) {
  __shared__ unsigned short lin[10 * 64 * 32];  // [row10][col64][32ic]  40960 B
  __shared__ unsigned short lw[9 * 64 * 32];    // [tap9][oc64][32ic]    36864 B

  // XCD-chunked swizzle: the 4 oc-tile sharers of one input tile stay on one XCD
  int bid = (blockIdx.x & 7) * 112 + (blockIdx.x >> 3);  // 896 = 8*112 bijective
  const int ot = bid & 3;
  const int g  = bid >> 2;               // 0..223 = n*7 + ht
  const int ht = g % 7, n = g / 7;
  const int h0 = ht * 8, oc0 = ot * 64;

  const int t = threadIdx.x;
  const int lane = t & 63, wv = t >> 6;
  const int cl = lane & 15, kk = lane >> 4;
  const int kswz = (kk ^ ((cl >> 1) & 3)) << 4;  // A-read slot offset (const/lane)

  for (int u = t; u < 10 * 64 * 4; u += 256)
    *(i32x4*)((char*)lin + (size_t)u * 16) = (i32x4){0, 0, 0, 0};

  int q0[7];  // r_out*64 + c_out per b-frag
#pragma unroll
  for (int nf = 0; nf < 7; ++nf) {
    int p = wv * 112 + nf * 16 + cl;
    q0[nf] = (p / 56) * 64 + (p % 56);
  }

  f32x4 acc[4][7];
#pragma unroll
  for (int m = 0; m < 4; ++m)
#pragma unroll
    for (int nf = 0; nf < 7; ++nf) acc[m][nf] = (f32x4){0.f, 0.f, 0.f, 0.f};

  __syncthreads();

  for (int icc = 0; icc < 8; ++icc) {
    // stage input rows (cols 1..56; halo stays zero); pre-swizzled source slots
    if (t < 224) {
      const int pw = t >> 2, sl = t & 3;
      const int srcslot = sl ^ (((1 + pw) >> 1) & 3);
#pragma unroll
      for (int rr = 0; rr < 10; ++rr) {
        int h = h0 - 1 + rr;
        if (h >= 0 && h < 56) {
          const char* src = (const char*)sIn +
              ((size_t)((n * 56 + h) * 56 + pw) * 512 + icc * 64 + srcslot * 16);
          char* dst = (char*)lin + ((rr * 64 + 1) * 64 + t * 16);
          gload_lds16(src, dst);
        }
      }
    }
    // stage weights: 2304 chunks, 9/thread, pre-swizzled source slots
#pragma unroll
    for (int i = 0; i < 9; ++i) {
      int u = i * 256 + t;
      int tap = u >> 8, oc_e = (u >> 2) & 63;
      int srcslot = (u & 3) ^ ((u >> 3) & 3);
      const unsigned short* src = wSgn +
          ((size_t)(tap * 256 + oc0 + oc_e) * 256 + icc * 32 + srcslot * 8);
      gload_lds16(src, (char*)lw + (size_t)u * 16);
    }
    __syncthreads();

#pragma unroll
    for (int kh = 0; kh < 3; ++kh)
#pragma unroll
      for (int kw = 0; kw < 3; ++kw) {
        const int tap = kh * 3 + kw;
        s16x8 a[4];
#pragma unroll
        for (int m = 0; m < 4; ++m)
          a[m] = *(const s16x8*)((const char*)lw + (tap * 64 + m * 16 + cl) * 64 + kswz);
#pragma unroll
        for (int nf = 0; nf < 7; ++nf) {
          int qq = q0[nf] + kw;
          int addr = (qq + kh * 64) * 64 + ((kk ^ ((qq >> 1) & 3)) << 4);
          s16x8 b = *(const s16x8*)((const char*)lin + addr);
#pragma unroll
          for (int m = 0; m < 4; ++m) acc[m][nf] = MFMA16(a[m], b, acc[m][nf]);
        }
      }
    __syncthreads();
  }

  // epilogue: int16 raw + stats
#pragma unroll
  for (int m = 0; m < 4; ++m) {
    float sm[4] = {0.f, 0.f, 0.f, 0.f}, sq[4] = {0.f, 0.f, 0.f, 0.f};
#pragma unroll
    for (int nf = 0; nf < 7; ++nf) {
      int p = wv * 112 + nf * 16 + cl;
      int h = h0 + p / 56, w = p % 56;
      size_t base = ((size_t)n * 256 + oc0 + m * 16 + kk * 4) * 3136 + h * 56 + w;
      f32x4 v = acc[m][nf];
#pragma unroll
      for (int r2 = 0; r2 < 4; ++r2) {
        raw[base + (size_t)r2 * 3136] = (short)(int)v[r2];
        sm[r2] += v[r2];
        sq[r2] += v[r2] * v[r2];
      }
    }
#pragma unroll
    for (int r2 = 0; r2 < 4; ++r2) {
      float aa = sm[r2], qq = sq[r2];
      aa += __shfl_xor(aa, 1); qq += __shfl_xor(qq, 1);
      aa += __shfl_xor(aa, 2); qq += __shfl_xor(qq, 2);
      aa += __shfl_xor(aa, 4); qq += __shfl_xor(qq, 4);
      aa += __shfl_xor(aa, 8); qq += __shfl_xor(qq, 8);
      if (cl == 0) {
        int oc = oc0 + m * 16 + kk * 4 + r2;
        atomicAdd(&S[oc], aa);
        atomicAdd(&SS[oc], qq);
      }
    }
  }
}

// ---------------------------------------------------------------------------
// conv1x1: block = 256 oc x 112 px; input read once; dbuf icc pipeline.
// 4 waves = 4 oc-groups (px shared). Wave: m=4 x nf=7.
// ---------------------------------------------------------------------------
__global__ __launch_bounds__(256, 2) void conv1x1(const unsigned short* __restrict__ sIn,
                                                  const unsigned short* __restrict__ wSgn,
                                                  short* __restrict__ raw,
                                                  float* __restrict__ S,
                                                  float* __restrict__ SS) {
  __shared__ unsigned short lin[2 * 112 * 32];  // 7168 B per buf
  __shared__ unsigned short lw[2 * 256 * 32];   // 16384 B per buf

  const int b = blockIdx.x;            // 896 = 28 * 32
  const int n = b / 28;
  const int hw0 = (b % 28) * 112;
  const size_t px0 = (size_t)n * 3136 + hw0;
  const int t = threadIdx.x, lane = t & 63, wv = t >> 6;
  const int cl = lane & 15, kk = lane >> 4;
  const int kswz = (kk ^ ((cl >> 1) & 3)) << 4;

#define STAGE_1x1(icc, bufi)                                                        \
  {                                                                                 \
    for (int u = t; u < 448; u += 256) {                                            \
      int srcslot = (u & 3) ^ ((u >> 3) & 3);                                       \
      const char* src = (const char*)sIn +                                          \
          ((px0 + (u >> 2)) * 512 + (icc) * 64 + srcslot * 16);                     \
      gload_lds16(src, (char*)lin + (bufi) * 7168 + u * 16);                        \
    }                                                                               \
    _Pragma("unroll")                                                               \
    for (int i = 0; i < 4; ++i) {                                                   \
      int u = i * 256 + t;                                                          \
      int srcslot = (u & 3) ^ ((u >> 3) & 3);                                       \
      const unsigned short* src = wSgn +                                            \
          ((size_t)(u >> 2) * 256 + (icc) * 32 + srcslot * 8);                      \
      gload_lds16(src, (char*)lw + (bufi) * 16384 + u * 16);                        \
    }                                                                               \
  }

  f32x4 acc[4][7];
#pragma unroll
  for (int m = 0; m < 4; ++m)
#pragma unroll
    for (int nf = 0; nf < 7; ++nf) acc[m][nf] = (f32x4){0.f, 0.f, 0.f, 0.f};

  STAGE_1x1(0, 0);
  __syncthreads();
  for (int icc = 0; icc < 8; ++icc) {
    const int cur = icc & 1;
    if (icc < 7) STAGE_1x1(icc + 1, cur ^ 1);
    s16x8 bfr[7];
#pragma unroll
    for (int nf = 0; nf < 7; ++nf)
      bfr[nf] = *(const s16x8*)((const char*)lin + cur * 7168 + (nf * 16 + cl) * 64 + kswz);
#pragma unroll
    for (int m = 0; m < 4; ++m) {
      s16x8 a = *(const s16x8*)((const char*)lw + cur * 16384 +
                                (wv * 64 + m * 16 + cl) * 64 + kswz);
#pragma unroll
      for (int nf = 0; nf < 7; ++nf) acc[m][nf] = MFMA16(a, bfr[nf], acc[m][nf]);
    }
    __syncthreads();
  }

#pragma unroll
  for (int m = 0; m < 4; ++m) {
    float sm[4] = {0.f, 0.f, 0.f, 0.f}, sq[4] = {0.f, 0.f, 0.f, 0.f};
    size_t base0 = ((size_t)n * 256 + wv * 64 + m * 16 + kk * 4) * 3136 + hw0;
#pragma unroll
    for (int nf = 0; nf < 7; ++nf) {
      f32x4 v = acc[m][nf];
#pragma unroll
      for (int r2 = 0; r2 < 4; ++r2) {
        raw[base0 + (size_t)r2 * 3136 + nf * 16 + cl] = (short)(int)v[r2];
        sm[r2] += v[r2];
        sq[r2] += v[r2] * v[r2];
      }
    }
#pragma unroll
    for (int r2 = 0; r2 < 4; ++r2) {
      float aa = sm[r2], qq = sq[r2];
      aa += __shfl_xor(aa, 1); qq += __shfl_xor(qq, 1);
      aa += __shfl_xor(aa, 2); qq += __shfl_xor(qq, 2);
      aa += __shfl_xor(aa, 4); qq += __shfl_xor(qq, 4);
      aa += __shfl_xor(aa, 8); qq += __shfl_xor(qq, 8);
      if (cl == 0) {
        int oc = wv * 64 + m * 16 + kk * 4 + r2;
        atomicAdd(&S[oc], aa);
        atomicAdd(&SS[oc], qq);
      }
    }
  }
}

// ---------------------------------------------------------------------------
// bn_coef: fold stats + scale + BN affine + following bias into A*raw + B
// ---------------------------------------------------------------------------
__global__ void bn_coef(const float* __restrict__ S, const float* __restrict__ SS,
                        const float* __restrict__ scale, const float* __restrict__ g,
                        const float* __restrict__ be, const float* __restrict__ bext,
                        float* __restrict__ A, float* __restrict__ B) {
  int o = threadIdx.x;
  const float invN = 1.f / 100352.f;
  float mu_r  = S[o] * invN;
  float var_r = SS[o] * invN - mu_r * mu_r;
  float sc    = scale[o];
  float rstd  = rsqrtf(sc * sc * var_r + 1e-5f);
  A[o] = g[o] * rstd * sc;
  B[o] = be[o] - g[o] * rstd * sc * mu_r + bext[o];
}

// ---------------------------------------------------------------------------
// mid_fuse: u = prelu(x + A1*raw + B1', p1) + b13 -> t1 (d_out, NCHW)
//           s2 = bf16(sign(u + b21)) (NHWC via swizzled LDS transpose)
// ---------------------------------------------------------------------------
__global__ __launch_bounds__(256) void mid_fuse(const short* __restrict__ raw,
                                                const float* __restrict__ x,
                                                const float* __restrict__ A1,
                                                const float* __restrict__ B1,
                                                const float* __restrict__ p1,
                                                const float* __restrict__ b13,
                                                const float* __restrict__ b21,
                                                float* __restrict__ t1,
                                                unsigned short* __restrict__ s2) {
  __shared__ unsigned short l[56 * 256];
  __shared__ float cA[256], cB[256], cP[256], cD[256], cE[256];
  const int h = blockIdx.x, n = blockIdx.y, t = threadIdx.x;
  cA[t] = A1[t]; cB[t] = B1[t]; cP[t] = p1[t]; cD[t] = b13[t]; cE[t] = b21[t];
  __syncthreads();
  const int wv = t & 15, cg = t >> 4;
  if (wv < 14) {
    const int w0 = wv * 4;
    const int swz = (wv & 7) << 3;
#pragma unroll 4
    for (int it = 0; it < 16; ++it) {
      int c = it * 16 + cg;
      size_t idx = (size_t)(n * 256 + c) * 3136 + h * 56 + w0;
      f32x4 xv = *(const f32x4*)(x + idx);
      s16x4 rv = *(const s16x4*)(raw + idx);
      float a = cA[c], b = cB[c], p = cP[c], d = cD[c], e = cE[c];
      f32x4 o;
      int cs = c ^ swz;
#pragma unroll
      for (int j = 0; j < 4; ++j) {
        float u = xv[j] + a * (float)rv[j] + b;
        u = (u >= 0.f ? u : p * u) + d;
        o[j] = u;
        l[(w0 + j) * 256 + cs] = sgnbits(u + e);
      }
      *(f32x4*)(t1 + idx) = o;
    }
  }
  __syncthreads();
  unsigned short* op = s2 + ((size_t)(n * 56 + h) * 56) * 256;
  for (int u = t; u < 56 * 32; u += 256) {
    int w2 = u >> 5, cp = u & 31;
    *(i32x4*)(op + w2 * 256 + cp * 8) =
        *(const i32x4*)&l[w2 * 256 + ((cp * 8) ^ (((w2 >> 2) & 7) << 3))];
  }
}

// ---------------------------------------------------------------------------
// final_fuse: out = prelu(A2*raw + B2' + t1, p2) + b23  (block per (n,c) plane)
// ---------------------------------------------------------------------------
__global__ __launch_bounds__(256) void final_fuse(const short* __restrict__ raw,
                                                  const float* __restrict__ A2,
                                                  const float* __restrict__ B2,
                                                  const float* __restrict__ p2,
                                                  const float* __restrict__ b23,
                                                  float* out) {
  const int c = blockIdx.x & 255;
  const size_t base = (size_t)blockIdx.x * 3136;
  const float a = A2[c], b = B2[c], p = p2[c], d = b23[c];
  for (int i = threadIdx.x; i < 784; i += 256) {
    s16x4 r  = *(const s16x4*)(raw + base + (size_t)i * 4);
    f32x4 tt = *(const f32x4*)(out + base + (size_t)i * 4);
    f32x4 o;
#pragma unroll
    for (int j = 0; j < 4; ++j) {
      float v = a * (float)r[j] + b + tt[j];
      o[j] = (v >= 0.f ? v : p * v) + d;
    }
    *(f32x4*)(out + base + (size_t)i * 4) = o;
  }
}

// ---------------------------------------------------------------------------
extern "C" void kernel_launch(void* const* d_in, const int* in_sizes, int n_in,
                              void* d_out, int out_size, void* d_ws, size_t ws_size,
                              hipStream_t stream) {
  const float* x   = (const float*)d_in[0];
  const float* b11 = (const float*)d_in[1];
  const float* b12 = (const float*)d_in[2];
  const float* b13 = (const float*)d_in[3];
  const float* b21 = (const float*)d_in[4];
  const float* b22 = (const float*)d_in[5];
  const float* b23 = (const float*)d_in[6];
  const float* w3  = (const float*)d_in[7];
  const float* wpw = (const float*)d_in[8];
  const float* g1  = (const float*)d_in[9];
  const float* be1 = (const float*)d_in[10];
  const float* g2  = (const float*)d_in[11];
  const float* be2 = (const float*)d_in[12];
  const float* p1  = (const float*)d_in[13];
  const float* p2  = (const float*)d_in[14];

  char* ws = (char*)d_ws;
  short*          raw    = (short*)(ws);                      //  51,380,224 B
  unsigned short* sgn    = (unsigned short*)(ws + 51380224);  //  51,380,224 B
  unsigned short* w1s    = (unsigned short*)(ws + 102760448); //   1,179,648 B
  unsigned short* w2s    = (unsigned short*)(ws + 103940096); //     131,072 B
  float*          scale1 = (float*)(ws + 104071168);
  float*          scale2 = (float*)(ws + 104072192);
  float*          S1     = (float*)(ws + 104073216);
  float*          SS1    = (float*)(ws + 104074240);
  float*          S2     = (float*)(ws + 104075264);
  float*          SS2    = (float*)(ws + 104076288);
  float*          A1     = (float*)(ws + 104077312);
  float*          B1     = (float*)(ws + 104078336);
  float*          A2     = (float*)(ws + 104079360);
  float*          B2     = (float*)(ws + 104080384);
  float*          t1     = (float*)d_out;

  hipMemsetAsync(ws + 104073216, 0, 4096, stream);  // zero S1,SS1,S2,SS2

  prep_w<<<dim3(256, 2), 256, 0, stream>>>(w3, wpw, w1s, w2s, scale1, scale2);
  sign_nhwc<<<dim3(56, 32), 256, 0, stream>>>(x, b11, sgn);
  conv3x3<<<dim3(896), 256, 0, stream>>>(sgn, w1s, raw, S1, SS1);
  bn_coef<<<1, 256, 0, stream>>>(S1, SS1, scale1, g1, be1, b12, A1, B1);
  mid_fuse<<<dim3(56, 32), 256, 0, stream>>>(raw, x, A1, B1, p1, b13, b21, t1, sgn);
  conv1x1<<<dim3(896), 256, 0, stream>>>(sgn, w2s, raw, S2, SS2);
  bn_coef<<<1, 256, 0, stream>>>(S2, SS2, scale2, g2, be2, b22, A2, B2);
  final_fuse<<<dim3(8192), 256, 0, stream>>>(raw, A2, B2, p2, b23, (float*)d_out);
}

// Round 4
// 385.137 us; speedup vs baseline: 1.4913x; 1.1279x over previous
//
#include <hip/hip_runtime.h>

typedef __attribute__((ext_vector_type(4))) float  f32x4;
typedef __attribute__((ext_vector_type(4))) short  s16x4;
typedef __attribute__((ext_vector_type(4))) int    i32x4;

#define MFMAI8(a, b, c) __builtin_amdgcn_mfma_i32_16x16x64_i8((a), (b), (c), 0, 0, 0)

__device__ __forceinline__ void gload_lds16(const void* g, void* l) {
  __builtin_amdgcn_global_load_lds((const __attribute__((address_space(1))) void*)g,
                                   (__attribute__((address_space(3))) void*)l, 16, 0, 0);
}

__device__ __forceinline__ char sgn8(float v) {
  return v > 0.f ? (char)1 : (v < 0.f ? (char)-1 : (char)0);
}

// ---------------------------------------------------------------------------
// prep_w: per-oc scale = mean|w|; sign(w) as int8.
//   y==0: w3x3 (C,C,3,3) -> w1s[tap][oc][ic] i8; scale1[oc]
//   y==1: wpw  (C,C,1,1) -> w2s[oc][ic] i8;      scale2[oc]
// ---------------------------------------------------------------------------
__global__ __launch_bounds__(256) void prep_w(const float* __restrict__ w3,
                                              const float* __restrict__ wpw,
                                              char* __restrict__ w1s,
                                              char* __restrict__ w2s,
                                              float* __restrict__ scale1,
                                              float* __restrict__ scale2) {
  const int o = blockIdx.x;
  const int t = threadIdx.x;
  float s = 0.f;
  if (blockIdx.y == 0) {
    for (int u = t; u < 2304; u += 256) {
      int i = u / 9, tap = u % 9;
      float v = w3[(size_t)(o * 256 + i) * 9 + tap];
      s += fabsf(v);
      w1s[(size_t)(tap * 256 + o) * 256 + i] = sgn8(v);
    }
  } else {
    float v = wpw[o * 256 + t];
    s = fabsf(v);
    w2s[o * 256 + t] = sgn8(v);
  }
  for (int m = 1; m < 64; m <<= 1) s += __shfl_xor(s, m);
  __shared__ float red[4];
  if ((t & 63) == 0) red[t >> 6] = s;
  __syncthreads();
  if (t == 0) {
    float tot = red[0] + red[1] + red[2] + red[3];
    if (blockIdx.y == 0) scale1[o] = tot / 2304.f;
    else                 scale2[o] = tot / 256.f;
  }
}

// ---------------------------------------------------------------------------
// sign_nhwc: s1[n][h][w][c] = i8 sign(x[n][c][h][w] + b11[c])
// channel-PAIR packing: u16 LDS transpose (2 B writes, swizzled 16 B reads).
// ---------------------------------------------------------------------------
__global__ __launch_bounds__(256) void sign_nhwc(const float* __restrict__ x,
                                                 const float* __restrict__ b11,
                                                 char* __restrict__ out) {
  __shared__ unsigned short l[56 * 128];  // [w][cpair]
  __shared__ float cB[256];
  const int h = blockIdx.x, n = blockIdx.y, t = threadIdx.x;
  cB[t] = b11[t];
  __syncthreads();
  const int wv = t & 15, cg = t >> 4;
  if (wv < 14) {
    const int w0 = wv * 4;
    const int swz = (wv & 7) << 3;
#pragma unroll 4
    for (int it = 0; it < 8; ++it) {
      int cp = it * 16 + cg;       // pair index 0..127
      int c0 = cp * 2;
      size_t i0 = (size_t)(n * 256 + c0) * 3136 + h * 56 + w0;
      f32x4 x0 = *(const f32x4*)(x + i0);
      f32x4 x1 = *(const f32x4*)(x + i0 + 3136);
      float bb0 = cB[c0], bb1 = cB[c0 + 1];
      int cs = cp ^ swz;
#pragma unroll
      for (int j = 0; j < 4; ++j) {
        unsigned short pk = (unsigned char)sgn8(x0[j] + bb0) |
                            ((unsigned short)(unsigned char)sgn8(x1[j] + bb1) << 8);
        l[(w0 + j) * 128 + cs] = pk;
      }
    }
  }
  __syncthreads();
  char* op = out + ((size_t)(n * 56 + h) * 56) * 256;
  for (int u = t; u < 56 * 16; u += 256) {
    int w2 = u >> 4, cp = u & 15;   // 16-byte chunk = 8 pairs
    *(i32x4*)(op + w2 * 256 + cp * 16) =
        *(const i32x4*)&l[w2 * 128 + ((cp * 8) ^ (((w2 >> 2) & 7) << 3))];
  }
}

// ---------------------------------------------------------------------------
// conv3x3: implicit-GEMM binary conv (i8), 3x3 pad1.
// Block: 64 oc x 448 px (8 rows x 56). Wave: m=4 x nf=7. 4 phases of 64 ic.
// LDS slot-XOR swizzle (conflict-free, byte-geometry identical to bf16 ver).
// ---------------------------------------------------------------------------
__global__ __launch_bounds__(256, 2) void conv3x3(const char* __restrict__ sIn,
                                                  const char* __restrict__ wSgn,
                                                  short* __restrict__ raw,
                                                  float* __restrict__ S,
                                                  float* __restrict__ SS) {
  __shared__ char lin[10 * 64 * 64];  // [row10][col64][64 ic-bytes]  40960 B
  __shared__ char lw[9 * 64 * 64];    // [tap9][oc64][64 ic-bytes]    36864 B

  int bid = (blockIdx.x & 7) * 112 + (blockIdx.x >> 3);  // XCD-chunked, bijective
  const int ot = bid & 3;
  const int g  = bid >> 2;
  const int ht = g % 7, n = g / 7;
  const int h0 = ht * 8, oc0 = ot * 64;

  const int t = threadIdx.x;
  const int lane = t & 63, wv = t >> 6;
  const int cl = lane & 15, kk = lane >> 4;
  const int kswz = (kk ^ ((cl >> 1) & 3)) << 4;  // A-read slot offset

  for (int u = t; u < 10 * 64 * 4; u += 256)
    *(i32x4*)(lin + (size_t)u * 16) = (i32x4){0, 0, 0, 0};

  int q0[7];
#pragma unroll
  for (int nf = 0; nf < 7; ++nf) {
    int p = wv * 112 + nf * 16 + cl;
    q0[nf] = (p / 56) * 64 + (p % 56);
  }

  i32x4 acc[4][7];
#pragma unroll
  for (int m = 0; m < 4; ++m)
#pragma unroll
    for (int nf = 0; nf < 7; ++nf) acc[m][nf] = (i32x4){0, 0, 0, 0};

  __syncthreads();

  for (int icc = 0; icc < 4; ++icc) {
    // stage input rows (cols 1..56; halo stays zero); pre-swizzled source slots
    if (t < 224) {
      const int pw = t >> 2, sl = t & 3;
      const int srcslot = sl ^ (((1 + pw) >> 1) & 3);
#pragma unroll
      for (int rr = 0; rr < 10; ++rr) {
        int h = h0 - 1 + rr;
        if (h >= 0 && h < 56) {
          const char* src = sIn +
              ((size_t)((n * 56 + h) * 56 + pw) * 256 + icc * 64 + srcslot * 16);
          gload_lds16(src, lin + ((rr * 64 + 1) * 64 + t * 16));
        }
      }
    }
    // stage weights: 2304 16B-chunks, 9/thread, pre-swizzled source slots
#pragma unroll
    for (int i = 0; i < 9; ++i) {
      int u = i * 256 + t;
      int tap = u >> 8, oc_e = (u >> 2) & 63;
      int srcslot = (u & 3) ^ ((u >> 3) & 3);
      const char* src = wSgn +
          ((size_t)(tap * 256 + oc0 + oc_e) * 256 + icc * 64 + srcslot * 16);
      gload_lds16(src, lw + (size_t)u * 16);
    }
    __syncthreads();

#pragma unroll
    for (int kh = 0; kh < 3; ++kh)
#pragma unroll
      for (int kw = 0; kw < 3; ++kw) {
        const int tap = kh * 3 + kw;
        i32x4 a[4];
#pragma unroll
        for (int m = 0; m < 4; ++m)
          a[m] = *(const i32x4*)(lw + (tap * 64 + m * 16 + cl) * 64 + kswz);
#pragma unroll
        for (int nf = 0; nf < 7; ++nf) {
          int qq = q0[nf] + kw;
          int addr = (qq + kh * 64) * 64 + ((kk ^ ((qq >> 1) & 3)) << 4);
          i32x4 b = *(const i32x4*)(lin + addr);
#pragma unroll
          for (int m = 0; m < 4; ++m) acc[m][nf] = MFMAI8(a[m], b, acc[m][nf]);
        }
      }
    __syncthreads();
  }

  // epilogue: int16 raw + stats
#pragma unroll
  for (int m = 0; m < 4; ++m) {
    float sm[4] = {0.f, 0.f, 0.f, 0.f}, sq[4] = {0.f, 0.f, 0.f, 0.f};
#pragma unroll
    for (int nf = 0; nf < 7; ++nf) {
      int p = wv * 112 + nf * 16 + cl;
      int h = h0 + p / 56, w = p % 56;
      size_t base = ((size_t)n * 256 + oc0 + m * 16 + kk * 4) * 3136 + h * 56 + w;
      i32x4 v = acc[m][nf];
#pragma unroll
      for (int r2 = 0; r2 < 4; ++r2) {
        raw[base + (size_t)r2 * 3136] = (short)v[r2];
        float fv = (float)v[r2];
        sm[r2] += fv;
        sq[r2] += fv * fv;
      }
    }
#pragma unroll
    for (int r2 = 0; r2 < 4; ++r2) {
      float aa = sm[r2], qq = sq[r2];
      aa += __shfl_xor(aa, 1); qq += __shfl_xor(qq, 1);
      aa += __shfl_xor(aa, 2); qq += __shfl_xor(qq, 2);
      aa += __shfl_xor(aa, 4); qq += __shfl_xor(qq, 4);
      aa += __shfl_xor(aa, 8); qq += __shfl_xor(qq, 8);
      if (cl == 0) {
        int oc = oc0 + m * 16 + kk * 4 + r2;
        atomicAdd(&S[oc], aa);
        atomicAdd(&SS[oc], qq);
      }
    }
  }
}

// ---------------------------------------------------------------------------
// conv1x1 (i8): block = 256 oc x 112 px; input read once; dbuf 4-phase pipeline.
// ---------------------------------------------------------------------------
__global__ __launch_bounds__(256, 2) void conv1x1(const char* __restrict__ sIn,
                                                  const char* __restrict__ wSgn,
                                                  short* __restrict__ raw,
                                                  float* __restrict__ S,
                                                  float* __restrict__ SS) {
  __shared__ char lin[2 * 112 * 64];  // 7168 B per buf
  __shared__ char lw[2 * 256 * 64];   // 16384 B per buf

  const int b = blockIdx.x;            // 896 = 28 * 32
  const int n = b / 28;
  const int hw0 = (b % 28) * 112;
  const size_t px0 = (size_t)n * 3136 + hw0;
  const int t = threadIdx.x, lane = t & 63, wv = t >> 6;
  const int cl = lane & 15, kk = lane >> 4;
  const int kswz = (kk ^ ((cl >> 1) & 3)) << 4;

#define STAGE_1x1(icc, bufi)                                                        \
  {                                                                                 \
    for (int u = t; u < 448; u += 256) {                                            \
      int srcslot = (u & 3) ^ ((u >> 3) & 3);                                       \
      const char* src = sIn + ((px0 + (u >> 2)) * 256 + (icc) * 64 + srcslot * 16); \
      gload_lds16(src, lin + (bufi) * 7168 + u * 16);                               \
    }                                                                               \
    _Pragma("unroll")                                                               \
    for (int i = 0; i < 4; ++i) {                                                   \
      int u = i * 256 + t;                                                          \
      int srcslot = (u & 3) ^ ((u >> 3) & 3);                                       \
      const char* src = wSgn + ((size_t)(u >> 2) * 256 + (icc) * 64 + srcslot * 16);\
      gload_lds16(src, lw + (bufi) * 16384 + u * 16);                               \
    }                                                                               \
  }

  i32x4 acc[4][7];
#pragma unroll
  for (int m = 0; m < 4; ++m)
#pragma unroll
    for (int nf = 0; nf < 7; ++nf) acc[m][nf] = (i32x4){0, 0, 0, 0};

  STAGE_1x1(0, 0);
  __syncthreads();
  for (int icc = 0; icc < 4; ++icc) {
    const int cur = icc & 1;
    if (icc < 3) STAGE_1x1(icc + 1, cur ^ 1);
    i32x4 bfr[7];
#pragma unroll
    for (int nf = 0; nf < 7; ++nf)
      bfr[nf] = *(const i32x4*)(lin + cur * 7168 + (nf * 16 + cl) * 64 + kswz);
#pragma unroll
    for (int m = 0; m < 4; ++m) {
      i32x4 a = *(const i32x4*)(lw + cur * 16384 + (wv * 64 + m * 16 + cl) * 64 + kswz);
#pragma unroll
      for (int nf = 0; nf < 7; ++nf) acc[m][nf] = MFMAI8(a, bfr[nf], acc[m][nf]);
    }
    __syncthreads();
  }

#pragma unroll
  for (int m = 0; m < 4; ++m) {
    float sm[4] = {0.f, 0.f, 0.f, 0.f}, sq[4] = {0.f, 0.f, 0.f, 0.f};
    size_t base0 = ((size_t)n * 256 + wv * 64 + m * 16 + kk * 4) * 3136 + hw0;
#pragma unroll
    for (int nf = 0; nf < 7; ++nf) {
      i32x4 v = acc[m][nf];
#pragma unroll
      for (int r2 = 0; r2 < 4; ++r2) {
        raw[base0 + (size_t)r2 * 3136 + nf * 16 + cl] = (short)v[r2];
        float fv = (float)v[r2];
        sm[r2] += fv;
        sq[r2] += fv * fv;
      }
    }
#pragma unroll
    for (int r2 = 0; r2 < 4; ++r2) {
      float aa = sm[r2], qq = sq[r2];
      aa += __shfl_xor(aa, 1); qq += __shfl_xor(qq, 1);
      aa += __shfl_xor(aa, 2); qq += __shfl_xor(qq, 2);
      aa += __shfl_xor(aa, 4); qq += __shfl_xor(qq, 4);
      aa += __shfl_xor(aa, 8); qq += __shfl_xor(qq, 8);
      if (cl == 0) {
        int oc = wv * 64 + m * 16 + kk * 4 + r2;
        atomicAdd(&S[oc], aa);
        atomicAdd(&SS[oc], qq);
      }
    }
  }
}

// ---------------------------------------------------------------------------
// bn_coef: fold stats + scale + BN affine + following bias into A*raw + B
// ---------------------------------------------------------------------------
__global__ void bn_coef(const float* __restrict__ S, const float* __restrict__ SS,
                        const float* __restrict__ scale, const float* __restrict__ g,
                        const float* __restrict__ be, const float* __restrict__ bext,
                        float* __restrict__ A, float* __restrict__ B) {
  int o = threadIdx.x;
  const float invN = 1.f / 100352.f;
  float mu_r  = S[o] * invN;
  float var_r = SS[o] * invN - mu_r * mu_r;
  float sc    = scale[o];
  float rstd  = rsqrtf(sc * sc * var_r + 1e-5f);
  A[o] = g[o] * rstd * sc;
  B[o] = be[o] - g[o] * rstd * sc * mu_r + bext[o];
}

// ---------------------------------------------------------------------------
// mid_fuse: u = prelu(x + A1*raw + B1', p1) + b13 -> t1 (d_out, NCHW f32)
//           s2 = i8 sign(u + b21) (NHWC, pair-packed LDS transpose)
// ---------------------------------------------------------------------------
__global__ __launch_bounds__(256) void mid_fuse(const short* __restrict__ raw,
                                                const float* __restrict__ x,
                                                const float* __restrict__ A1,
                                                const float* __restrict__ B1,
                                                const float* __restrict__ p1,
                                                const float* __restrict__ b13,
                                                const float* __restrict__ b21,
                                                float* __restrict__ t1,
                                                char* __restrict__ s2) {
  __shared__ unsigned short l[56 * 128];
  __shared__ float cA[256], cB[256], cP[256], cD[256], cE[256];
  const int h = blockIdx.x, n = blockIdx.y, t = threadIdx.x;
  cA[t] = A1[t]; cB[t] = B1[t]; cP[t] = p1[t]; cD[t] = b13[t]; cE[t] = b21[t];
  __syncthreads();
  const int wv = t & 15, cg = t >> 4;
  if (wv < 14) {
    const int w0 = wv * 4;
    const int swz = (wv & 7) << 3;
#pragma unroll 2
    for (int it = 0; it < 8; ++it) {
      int cp = it * 16 + cg;
      int c0 = cp * 2;
      size_t i0 = (size_t)(n * 256 + c0) * 3136 + h * 56 + w0;
      f32x4 x0 = *(const f32x4*)(x + i0);
      f32x4 x1 = *(const f32x4*)(x + i0 + 3136);
      s16x4 r0 = *(const s16x4*)(raw + i0);
      s16x4 r1 = *(const s16x4*)(raw + i0 + 3136);
      float a0 = cA[c0], b0 = cB[c0], p0 = cP[c0], d0 = cD[c0], e0 = cE[c0];
      float a1 = cA[c0+1], b1 = cB[c0+1], p1v = cP[c0+1], d1 = cD[c0+1], e1 = cE[c0+1];
      f32x4 o0, o1;
      int cs = cp ^ swz;
#pragma unroll
      for (int j = 0; j < 4; ++j) {
        float u0 = x0[j] + a0 * (float)r0[j] + b0;
        u0 = (u0 >= 0.f ? u0 : p0 * u0) + d0;
        o0[j] = u0;
        float u1 = x1[j] + a1 * (float)r1[j] + b1;
        u1 = (u1 >= 0.f ? u1 : p1v * u1) + d1;
        o1[j] = u1;
        unsigned short pk = (unsigned char)sgn8(u0 + e0) |
                            ((unsigned short)(unsigned char)sgn8(u1 + e1) << 8);
        l[(w0 + j) * 128 + cs] = pk;
      }
      *(f32x4*)(t1 + i0) = o0;
      *(f32x4*)(t1 + i0 + 3136) = o1;
    }
  }
  __syncthreads();
  char* op = s2 + ((size_t)(n * 56 + h) * 56) * 256;
  for (int u = t; u < 56 * 16; u += 256) {
    int w2 = u >> 4, cp = u & 15;
    *(i32x4*)(op + w2 * 256 + cp * 16) =
        *(const i32x4*)&l[w2 * 128 + ((cp * 8) ^ (((w2 >> 2) & 7) << 3))];
  }
}

// ---------------------------------------------------------------------------
// final_fuse: out = prelu(A2*raw + B2' + t1, p2) + b23  (block per (n,c) plane)
// ---------------------------------------------------------------------------
__global__ __launch_bounds__(256) void final_fuse(const short* __restrict__ raw,
                                                  const float* __restrict__ A2,
                                                  const float* __restrict__ B2,
                                                  const float* __restrict__ p2,
                                                  const float* __restrict__ b23,
                                                  float* out) {
  const int c = blockIdx.x & 255;
  const size_t base = (size_t)blockIdx.x * 3136;
  const float a = A2[c], b = B2[c], p = p2[c], d = b23[c];
  for (int i = threadIdx.x; i < 784; i += 256) {
    s16x4 r  = *(const s16x4*)(raw + base + (size_t)i * 4);
    f32x4 tt = *(const f32x4*)(out + base + (size_t)i * 4);
    f32x4 o;
#pragma unroll
    for (int j = 0; j < 4; ++j) {
      float v = a * (float)r[j] + b + tt[j];
      o[j] = (v >= 0.f ? v : p * v) + d;
    }
    *(f32x4*)(out + base + (size_t)i * 4) = o;
  }
}

// ---------------------------------------------------------------------------
extern "C" void kernel_launch(void* const* d_in, const int* in_sizes, int n_in,
                              void* d_out, int out_size, void* d_ws, size_t ws_size,
                              hipStream_t stream) {
  const float* x   = (const float*)d_in[0];
  const float* b11 = (const float*)d_in[1];
  const float* b12 = (const float*)d_in[2];
  const float* b13 = (const float*)d_in[3];
  const float* b21 = (const float*)d_in[4];
  const float* b22 = (const float*)d_in[5];
  const float* b23 = (const float*)d_in[6];
  const float* w3  = (const float*)d_in[7];
  const float* wpw = (const float*)d_in[8];
  const float* g1  = (const float*)d_in[9];
  const float* be1 = (const float*)d_in[10];
  const float* g2  = (const float*)d_in[11];
  const float* be2 = (const float*)d_in[12];
  const float* p1  = (const float*)d_in[13];
  const float* p2  = (const float*)d_in[14];

  char* ws = (char*)d_ws;
  short* raw    = (short*)(ws);                //  51,380,224 B
  char*  sgn    = (char*)(ws + 51380224);      //  25,690,112 B
  char*  w1s    = (char*)(ws + 77070336);      //     589,824 B
  char*  w2s    = (char*)(ws + 77660160);      //      65,536 B
  float* scale1 = (float*)(ws + 77725696);
  float* scale2 = (float*)(ws + 77726720);
  float* S1     = (float*)(ws + 77727744);
  float* SS1    = (float*)(ws + 77728768);
  float* S2     = (float*)(ws + 77729792);
  float* SS2    = (float*)(ws + 77730816);
  float* A1     = (float*)(ws + 77731840);
  float* B1     = (float*)(ws + 77732864);
  float* A2     = (float*)(ws + 77733888);
  float* B2     = (float*)(ws + 77734912);
  float* t1     = (float*)d_out;

  hipMemsetAsync(ws + 77727744, 0, 4096, stream);  // zero S1,SS1,S2,SS2

  prep_w<<<dim3(256, 2), 256, 0, stream>>>(w3, wpw, w1s, w2s, scale1, scale2);
  sign_nhwc<<<dim3(56, 32), 256, 0, stream>>>(x, b11, sgn);
  conv3x3<<<dim3(896), 256, 0, stream>>>(sgn, w1s, raw, S1, SS1);
  bn_coef<<<1, 256, 0, stream>>>(S1, SS1, scale1, g1, be1, b12, A1, B1);
  mid_fuse<<<dim3(56, 32), 256, 0, stream>>>(raw, x, A1, B1, p1, b13, b21, t1, sgn);
  conv1x1<<<dim3(896), 256, 0, stream>>>(sgn, w2s, raw, S2, SS2);
  bn_coef<<<1, 256, 0, stream>>>(S2, SS2, scale2, g2, be2, b22, A2, B2);
  final_fuse<<<dim3(8192), 256, 0, stream>>>(raw, A2, B2, p2, b23, (float*)d_out);
}